// Round 1
// baseline (123.784 us; speedup 1.0000x reference)
//
#include <hip/hip_runtime.h>
#include <math.h>

#define TI 128
#define TJ 128
#define NTHREADS 256

__device__ __forceinline__ float fast_exp2(float x) {
#if __has_builtin(__builtin_amdgcn_exp2f)
    return __builtin_amdgcn_exp2f(x);
#else
    return exp2f(x);
#endif
}
__device__ __forceinline__ float fast_rcp(float x) {
#if __has_builtin(__builtin_amdgcn_rcpf)
    return __builtin_amdgcn_rcpf(x);
#else
    return 1.0f / x;
#endif
}
__device__ __forceinline__ float fast_sqrt(float x) {
#if __has_builtin(__builtin_amdgcn_sqrtf)
    return __builtin_amdgcn_sqrtf(x);
#else
    return sqrtf(x);
#endif
}

// sigmoid(thr - d) = 1 / (1 + exp(d) * exp(-thr)); exp(d) computed once.
#define C0 0.60653065971263342360f  /* exp(-0.5) */
#define C1 0.36787944117144232160f  /* exp(-1)   */
#define C2 0.13533528323661269189f  /* exp(-2)   */
#define C3 0.01831563888873418029f  /* exp(-4)   */
#define LOG2E 1.44269504088896340736f

__global__ __launch_bounds__(NTHREADS) void lddt_tile_kernel(
    const float* __restrict__ pred, const float* __restrict__ tru,
    const int* __restrict__ is_dna, const int* __restrict__ is_rna,
    const int* __restrict__ cmask,
    double* __restrict__ num_out, unsigned int* __restrict__ den_out,
    int n, int tiles_per_row)
{
    __shared__ float4 sA[TJ];   // (pjx, pjy, pjz, tjx)
    __shared__ float4 sB[TJ];   // (tjy, tjz, nt_j, cm_j)
    __shared__ float wnum[NTHREADS / 64];
    __shared__ unsigned int wden[NTHREADS / 64];

    const int tiles_per_batch = tiles_per_row * tiles_per_row;
    const int bi = blockIdx.x / tiles_per_batch;
    const int t  = blockIdx.x % tiles_per_batch;
    const int ti = t / tiles_per_row;
    const int tj = t % tiles_per_row;
    const int i0 = ti * TI;
    const int j0 = tj * TJ;

    const int tid = threadIdx.x;
    const size_t base = (size_t)bi * n;

    // ---- stage j-tile into LDS ----
    if (tid < TJ) {
        const int j = j0 + tid;
        const float* p = pred + (base + j) * 3;
        const float* q = tru  + (base + j) * 3;
        const float ntj = ((is_dna[base + j] != 0) | (is_rna[base + j] != 0)) ? 1.0f : 0.0f;
        const float cmj = (cmask[base + j] != 0) ? 1.0f : 0.0f;
        sA[tid] = make_float4(p[0], p[1], p[2], q[0]);
        sB[tid] = make_float4(q[1], q[2], ntj, cmj);
    }
    __syncthreads();

    // ---- per-thread row data (2 threads per i, 64 j's each) ----
    const int il = tid & (TI - 1);
    const int i  = i0 + il;
    const float* p = pred + (base + i) * 3;
    const float* q = tru  + (base + i) * 3;
    const float pix = p[0], piy = p[1], piz = p[2];
    const float tix = q[0], tiy = q[1], tiz = q[2];
    const bool nti = ((is_dna[base + i] != 0) | (is_rna[base + i] != 0));
    const bool cmi = (cmask[base + i] != 0);

    float fnum = 0.0f;
    unsigned int iden = 0u;

    const int kbase = (tid >> 7) * (TJ / 2);   // 0 or 64

    #pragma unroll 4
    for (int k = 0; k < TJ / 2; ++k) {
        const int jl = kbase + k;
        const float4 A = sA[jl];
        const float4 B = sB[jl];

        const float dxp = pix - A.x, dyp = piy - A.y, dzp = piz - A.z;
        const float sqp = dxp * dxp + dyp * dyp + dzp * dzp;
        const float dxt = tix - A.w, dyt = tiy - B.x, dzt = tiz - B.y;
        const float sqt = dxt * dxt + dyt * dyt + dzt * dzt;

        const float dp = fast_sqrt(sqp);   // sqrt(0)=0, matches safe-sqrt fwd value
        const float dt = fast_sqrt(sqt);

        const float diff = fabsf(dt - dp);
        const float e = fast_exp2(diff * LOG2E);   // exp(diff); overflow -> inf -> rcp -> 0 (correct)

        const float s = fast_rcp(fmaf(e, C0, 1.0f))
                      + fast_rcp(fmaf(e, C1, 1.0f))
                      + fast_rcp(fmaf(e, C2, 1.0f))
                      + fast_rcp(fmaf(e, C3, 1.0f));

        const float cutoff = (nti && (B.z != 0.0f)) ? 30.0f : 15.0f;
        const bool m = (dt < cutoff) && cmi && (B.w != 0.0f) && ((j0 + jl) != i);

        fnum += m ? s : 0.0f;
        iden += m ? 1u : 0u;
    }

    // ---- wave reduce (width 64) ----
    #pragma unroll
    for (int off = 32; off > 0; off >>= 1) {
        fnum += __shfl_down(fnum, off, 64);
        iden += __shfl_down(iden, off, 64);
    }
    const int wave = tid >> 6;
    if ((tid & 63) == 0) { wnum[wave] = fnum; wden[wave] = iden; }
    __syncthreads();

    if (tid == 0) {
        float tn = 0.0f;
        unsigned int td = 0u;
        #pragma unroll
        for (int w = 0; w < NTHREADS / 64; ++w) { tn += wnum[w]; td += wden[w]; }
        atomicAdd(&num_out[bi], (double)tn);
        atomicAdd(&den_out[bi], td);
    }
}

__global__ void lddt_final_kernel(const double* __restrict__ num,
                                  const unsigned int* __restrict__ den,
                                  float* __restrict__ out)
{
    // eps mean over 4 thresholds -> 0.25 factor applied here
    const double d0 = (double)(den[0] > 1u ? den[0] : 1u);
    const double d1 = (double)(den[1] > 1u ? den[1] : 1u);
    const double l0 = num[0] * 0.25 / d0;
    const double l1 = num[1] * 0.25 / d1;
    out[0] = (float)(1.0 - 0.5 * (l0 + l1));
}

extern "C" void kernel_launch(void* const* d_in, const int* in_sizes, int n_in,
                              void* d_out, int out_size, void* d_ws, size_t ws_size,
                              hipStream_t stream) {
    const float* pred  = (const float*)d_in[0];
    const float* tru   = (const float*)d_in[1];
    const int*   dna   = (const int*)d_in[2];
    const int*   rna   = (const int*)d_in[3];
    const int*   cm    = (const int*)d_in[4];
    float* out = (float*)d_out;

    const int B = 2;
    const int n = in_sizes[2] / B;   // is_dna has b*n elements

    double* num = (double*)d_ws;
    unsigned int* den = (unsigned int*)((char*)d_ws + 2 * sizeof(double));

    hipMemsetAsync(d_ws, 0, 2 * sizeof(double) + 2 * sizeof(unsigned int), stream);

    const int tiles_per_row = n / TJ;   // n=4096 divisible by 128
    const int grid = B * tiles_per_row * tiles_per_row;

    hipLaunchKernelGGL(lddt_tile_kernel, dim3(grid), dim3(NTHREADS), 0, stream,
                       pred, tru, dna, rna, cm, num, den, n, tiles_per_row);
    hipLaunchKernelGGL(lddt_final_kernel, dim3(1), dim3(1), 0, stream, num, den, out);
}

// Round 2
// 97.870 us; speedup vs baseline: 1.2648x; 1.2648x over previous
//
#include <hip/hip_runtime.h>
#include <math.h>

#define TS 64
#define NTHREADS 256
#define JPT (TS * TS / NTHREADS)   // 16 j's per thread

__device__ __forceinline__ float fast_exp2(float x) {
#if __has_builtin(__builtin_amdgcn_exp2f)
    return __builtin_amdgcn_exp2f(x);
#else
    return exp2f(x);
#endif
}
__device__ __forceinline__ float fast_rcp(float x) {
#if __has_builtin(__builtin_amdgcn_rcpf)
    return __builtin_amdgcn_rcpf(x);
#else
    return 1.0f / x;
#endif
}
__device__ __forceinline__ float fast_sqrt(float x) {
#if __has_builtin(__builtin_amdgcn_sqrtf)
    return __builtin_amdgcn_sqrtf(x);
#else
    return sqrtf(x);
#endif
}

// sigmoid(thr - d) = 1/(1 + exp(d)*exp(-thr)); the 4 sigmoids combined over a
// common denominator -> ONE rcp per pair instead of four.
#define C0 0.60653065971263342360f  /* exp(-0.5) */
#define C1 0.36787944117144232160f  /* exp(-1)   */
#define C2 0.13533528323661269189f  /* exp(-2)   */
#define C3 0.01831563888873418029f  /* exp(-4)   */
#define LOG2E 1.44269504088896340736f
// sigma(0.5)+sigma(1)+sigma(2)+sigma(4): self-pair (diff=0) contribution
#define S_DIAG 3.2163287777874683f
// clamp exp2 arg: keeps e^4 * C0*C1*C2*C3 finite; sigmoid tail < 1.2e-7 there
#define EXP2_CLAMP 30.0f

__global__ __launch_bounds__(NTHREADS) void lddt_tile_kernel(
    const float* __restrict__ pred, const float* __restrict__ tru,
    const int* __restrict__ is_dna, const int* __restrict__ is_rna,
    const int* __restrict__ cmask,
    float* __restrict__ pnum, unsigned int* __restrict__ pden,
    int n, int T)
{
    __shared__ float4 sA[TS];   // pjx, pjy, pjz, tjx
    __shared__ float4 sB[TS];   // tjy, tjz, cut_if_nt_i, cut_if_not_nt_i (0 if !cm_j)
    __shared__ float wnum[NTHREADS / 64];
    __shared__ unsigned int wden[NTHREADS / 64];

    const int tpb = T * T;
    const int bi = blockIdx.x / tpb;
    const int t  = blockIdx.x % tpb;
    const int ti = t / T;
    const int tj = t % T;
    if (ti > tj) return;              // symmetric: only upper triangle of tiles
    const bool diag = (ti == tj);
    const int i0 = ti * TS, j0 = tj * TS;
    const int tid = threadIdx.x;
    const size_t base = (size_t)bi * n;

    // ---- stage j-tile (cm_j & nt_j folded into per-j cutoffs) ----
    if (tid < TS) {
        const int j = j0 + tid;
        const float* p = pred + (base + j) * 3;
        const float* q = tru  + (base + j) * 3;
        const bool ntj = (is_dna[base + j] != 0) || (is_rna[base + j] != 0);
        const bool cmj = (cmask[base + j] != 0);
        const float cut_nt = cmj ? (ntj ? 30.0f : 15.0f) : 0.0f;  // dt<0 impossible
        const float cut_o  = cmj ? 15.0f : 0.0f;
        sA[tid] = make_float4(p[0], p[1], p[2], q[0]);
        sB[tid] = make_float4(q[1], q[2], cut_nt, cut_o);
    }
    __syncthreads();

    // ---- per-thread row data: 4 threads per row i, JPT j's each ----
    const int il = tid & (TS - 1);
    const int i  = i0 + il;
    const float* p = pred + (base + i) * 3;
    const float* q = tru  + (base + i) * 3;
    const float pix = p[0], piy = p[1], piz = p[2];
    const float tix = q[0], tiy = q[1], tiz = q[2];
    const bool nti = (is_dna[base + i] != 0) || (is_rna[base + i] != 0);
    const bool cmi = (cmask[base + i] != 0);
    const float cmf = cmi ? 1.0f : 0.0f;

    float fnum = 0.0f;
    unsigned int iden = 0u;
    const int kbase = (tid >> 6) * JPT;   // wave-uniform -> LDS broadcast reads

    #pragma unroll 4
    for (int k = 0; k < JPT; ++k) {
        const int jl = kbase + k;
        const float4 A  = sA[jl];
        const float4 Bv = sB[jl];

        const float dxp = pix - A.x, dyp = piy - A.y, dzp = piz - A.z;
        const float sqp = fmaf(dxp, dxp, fmaf(dyp, dyp, dzp * dzp));
        const float dxt = tix - A.w, dyt = tiy - Bv.x, dzt = tiz - Bv.y;
        const float sqt = fmaf(dxt, dxt, fmaf(dyt, dyt, dzt * dzt));

        const float dp = fast_sqrt(sqp);
        const float dt = fast_sqrt(sqt);

        const float x = fminf(fabsf(dt - dp) * LOG2E, EXP2_CLAMP);
        const float e = fast_exp2(x);                 // exp(|d_t - d_p|)

        const float t0 = fmaf(e, C0, 1.0f), t1 = fmaf(e, C1, 1.0f);
        const float t2 = fmaf(e, C2, 1.0f), t3 = fmaf(e, C3, 1.0f);
        const float q1 = t0 * t1, q2 = t2 * t3;
        const float p1 = t0 + t1, p2 = t2 + t3;
        const float s = fmaf(p1, q2, p2 * q1) * fast_rcp(q1 * q2);

        const float cutoff = nti ? Bv.z : Bv.w;       // cm_j folded in (0 kills)
        const bool m = dt < cutoff;
        fnum += m ? s : 0.0f;
        iden += m ? 1u : 0u;
    }

    // fold row cm_i; remove self-pair contribution on diagonal tiles
    fnum *= cmf;
    iden = cmi ? iden : 0u;
    if (diag && tid < TS) {           // exactly once per row i
        fnum -= cmf * S_DIAG;
        iden -= cmi ? 1u : 0u;        // modular across block sum: total is exact
    }

    // ---- wave (64) then block reduction ----
    #pragma unroll
    for (int off = 32; off > 0; off >>= 1) {
        fnum += __shfl_down(fnum, off, 64);
        iden += __shfl_down(iden, off, 64);
    }
    const int w = tid >> 6;
    if ((tid & 63) == 0) { wnum[w] = fnum; wden[w] = iden; }
    __syncthreads();

    if (tid == 0) {
        const float tn = wnum[0] + wnum[1] + wnum[2] + wnum[3];
        const unsigned int td = wden[0] + wden[1] + wden[2] + wden[3];
        // compact triangular slot: every slot gets written -> no ws zero-init
        const int slot = bi * (T * (T + 1) / 2) + ti * T - ti * (ti - 1) / 2 + (tj - ti);
        pnum[slot] = diag ? tn : tn * 2.0f;
        pden[slot] = diag ? td : td * 2u;
    }
}

__global__ __launch_bounds__(256) void lddt_final_kernel(
    const float* __restrict__ pnum, const unsigned int* __restrict__ pden,
    float* __restrict__ out, int nslots)
{
    __shared__ double sn0[4], sn1[4], sd0[4], sd1[4];
    double n0 = 0, n1 = 0, d0 = 0, d1 = 0;
    for (int s = threadIdx.x; s < 2 * nslots; s += 256) {
        if (s < nslots) { n0 += (double)pnum[s]; d0 += (double)pden[s]; }
        else            { n1 += (double)pnum[s]; d1 += (double)pden[s]; }
    }
    #pragma unroll
    for (int off = 32; off > 0; off >>= 1) {
        n0 += __shfl_down(n0, off, 64); d0 += __shfl_down(d0, off, 64);
        n1 += __shfl_down(n1, off, 64); d1 += __shfl_down(d1, off, 64);
    }
    const int w = threadIdx.x >> 6;
    if ((threadIdx.x & 63) == 0) { sn0[w] = n0; sn1[w] = n1; sd0[w] = d0; sd1[w] = d1; }
    __syncthreads();
    if (threadIdx.x == 0) {
        double N0 = sn0[0] + sn0[1] + sn0[2] + sn0[3];
        double N1 = sn1[0] + sn1[1] + sn1[2] + sn1[3];
        double D0 = sd0[0] + sd0[1] + sd0[2] + sd0[3];
        double D1 = sd1[0] + sd1[1] + sd1[2] + sd1[3];
        D0 = D0 > 1.0 ? D0 : 1.0;
        D1 = D1 > 1.0 ? D1 : 1.0;
        const double l0 = 0.25 * N0 / D0;   // 0.25 = mean over 4 thresholds
        const double l1 = 0.25 * N1 / D1;
        out[0] = (float)(1.0 - 0.5 * (l0 + l1));
    }
}

extern "C" void kernel_launch(void* const* d_in, const int* in_sizes, int n_in,
                              void* d_out, int out_size, void* d_ws, size_t ws_size,
                              hipStream_t stream) {
    const float* pred = (const float*)d_in[0];
    const float* tru  = (const float*)d_in[1];
    const int*   dna  = (const int*)d_in[2];
    const int*   rna  = (const int*)d_in[3];
    const int*   cm   = (const int*)d_in[4];
    float* out = (float*)d_out;

    const int B = 2;
    const int n = in_sizes[2] / B;        // is_dna has b*n elements
    const int T = n / TS;                 // 64 tiles per row
    const int nslots = T * (T + 1) / 2;   // 2080 per batch

    float* pnum = (float*)d_ws;
    unsigned int* pden = (unsigned int*)((char*)d_ws + (size_t)2 * nslots * sizeof(float));

    const int grid = B * T * T;           // ti>tj blocks exit immediately

    hipLaunchKernelGGL(lddt_tile_kernel, dim3(grid), dim3(NTHREADS), 0, stream,
                       pred, tru, dna, rna, cm, pnum, pden, n, T);
    hipLaunchKernelGGL(lddt_final_kernel, dim3(1), dim3(256), 0, stream,
                       pnum, pden, out, nslots);
}

// Round 3
// 85.808 us; speedup vs baseline: 1.4426x; 1.1406x over previous
//
#include <hip/hip_runtime.h>
#include <math.h>

#define TS 64
#define NTHREADS 256
#define JPT 16                      // j's per thread (4 quads)
#define LUTN 512
#define LUT_DMAX 12.0f
#define LUT_SCALE ((float)LUTN / LUT_DMAX)
// sigma(0.5)+sigma(1)+sigma(2)+sigma(4): self-pair (diff=0) contribution
#define S_DIAG 3.2163287777874683f

typedef float v2f __attribute__((ext_vector_type(2)));

__device__ __forceinline__ float fsqrt(float x) {
#if __has_builtin(__builtin_amdgcn_sqrtf)
    return __builtin_amdgcn_sqrtf(x);
#else
    return sqrtf(x);
#endif
}

// f(d) = sum of 4 sigmoids sigma(thr - d); build-time only (exact path)
__device__ __forceinline__ float sig4(float d) {
    const float e = expf(d);
    return 1.0f / (1.0f + e * 0.60653065971263342360f)   // exp(-0.5)
         + 1.0f / (1.0f + e * 0.36787944117144232160f)   // exp(-1)
         + 1.0f / (1.0f + e * 0.13533528323661269189f)   // exp(-2)
         + 1.0f / (1.0f + e * 0.01831563888873418029f);  // exp(-4)
}

__device__ __forceinline__ void pair_tail(float sqp, float sqt, float cut,
                                          const float2* __restrict__ lut,
                                          float& num, float& den) {
    const float dp = fsqrt(sqp);
    const float dt = fsqrt(sqt);
    float u = fabsf(dt - dp) * LUT_SCALE;
    u = fminf(u, (float)LUTN - 0.001f);
    const int idx = (int)u;
    const float fr = u - (float)idx;
    const float2 L = lut[idx];                 // {f_lo, f_hi - f_lo}
    const float s = fmaf(fr, L.y, L.x);
    const float m = (dt < cut) ? 1.0f : 0.0f;  // cut=0 when !cm_j kills pair
    num = fmaf(m, s, num);
    den += m;
}

__global__ __launch_bounds__(NTHREADS) void lddt_tile_kernel(
    const float* __restrict__ pred, const float* __restrict__ tru,
    const int* __restrict__ is_dna, const int* __restrict__ is_rna,
    const int* __restrict__ cmask,
    float* __restrict__ pnum, float* __restrict__ pden,
    int n, int T, int nslots)
{
    __shared__ __align__(16) float sPX[TS], sPY[TS], sPZ[TS];
    __shared__ __align__(16) float sTX[TS], sTY[TS], sTZ[TS];
    __shared__ __align__(16) float sCut[2 * TS];   // [nt_i cutoffs | other cutoffs]
    __shared__ float2 sLUT[LUTN];
    __shared__ float wnum[4], wden[4];

    const int tid = threadIdx.x;

    // ---- decode block -> (bi, ti, tj) over upper-triangular tiles ----
    int slot = blockIdx.x;
    const int bi = slot / nslots;
    slot -= bi * nslots;
    const int W = 2 * T + 1;
    int ti = (int)(((float)W - fsqrt((float)(W * W - 8 * slot))) * 0.5f);
    while ((ti + 1) * (W - (ti + 1)) / 2 <= slot) ++ti;   // fixup fp rounding
    while (ti * (W - ti) / 2 > slot) --ti;
    const int tj = ti + (slot - ti * (W - ti) / 2);
    const bool diag = (ti == tj);
    const int i0 = ti * TS, j0 = tj * TS;
    const size_t base = (size_t)bi * n;

    // ---- stage j-tile (SoA) + per-j cutoffs (cm_j & nt_j folded in) ----
    if (tid < TS) {
        const int j = j0 + tid;
        const float* p = pred + (base + j) * 3;
        const float* q = tru  + (base + j) * 3;
        sPX[tid] = p[0]; sPY[tid] = p[1]; sPZ[tid] = p[2];
        sTX[tid] = q[0]; sTY[tid] = q[1]; sTZ[tid] = q[2];
        const bool ntj = (is_dna[base + j] != 0) || (is_rna[base + j] != 0);
        const bool cmj = (cmask[base + j] != 0);
        sCut[tid]      = cmj ? (ntj ? 30.0f : 15.0f) : 0.0f;
        sCut[TS + tid] = cmj ? 15.0f : 0.0f;
    }

    // ---- build f(d) linear-interp LUT on [0, LUT_DMAX] ----
    for (int e = tid; e < LUTN; e += NTHREADS) {
        const float d0 = (float)e * (LUT_DMAX / LUTN);
        const float f0 = sig4(d0);
        const float f1 = sig4(d0 + (LUT_DMAX / LUTN));
        sLUT[e] = make_float2(f0, f1 - f0);
    }

    // ---- per-thread row data: 4 waves x 64 rows; wave w covers 16 j's ----
    const int il = tid & (TS - 1);
    const int i  = i0 + il;
    const float* p = pred + (base + i) * 3;
    const float* q = tru  + (base + i) * 3;
    const float pix = p[0], piy = p[1], piz = p[2];
    const float tix = q[0], tiy = q[1], tiz = q[2];
    const bool nti = (is_dna[base + i] != 0) || (is_rna[base + i] != 0);
    const float cmf = (cmask[base + i] != 0) ? 1.0f : 0.0f;
    __syncthreads();

    const float* cutsel = nti ? &sCut[0] : &sCut[TS];
    const int kbase = (tid >> 6) * JPT;   // wave-uniform -> LDS broadcast reads

    float num = 0.0f, den = 0.0f;
    const v2f px2 = {pix, pix}, py2 = {piy, piy}, pz2 = {piz, piz};
    const v2f tx2 = {tix, tix}, ty2 = {tiy, tiy}, tz2 = {tiz, tiz};

    #pragma unroll
    for (int qd = 0; qd < JPT / 4; ++qd) {
        const int jq = kbase + 4 * qd;
        const float4 PX = *(const float4*)&sPX[jq];
        const float4 PY = *(const float4*)&sPY[jq];
        const float4 PZ = *(const float4*)&sPZ[jq];
        const float4 TX = *(const float4*)&sTX[jq];
        const float4 TY = *(const float4*)&sTY[jq];
        const float4 TZ = *(const float4*)&sTZ[jq];
        const float4 CT = *(const float4*)&cutsel[jq];

        // duo A = (j, j+1), duo B = (j+2, j+3): packed f32 distance math
        v2f dx, dy, dz, sqpA, sqpB, sqtA, sqtB;

        dx = px2 - (v2f){PX.x, PX.y}; dy = py2 - (v2f){PY.x, PY.y}; dz = pz2 - (v2f){PZ.x, PZ.y};
        sqpA = dx * dx + dy * dy + dz * dz;
        dx = tx2 - (v2f){TX.x, TX.y}; dy = ty2 - (v2f){TY.x, TY.y}; dz = tz2 - (v2f){TZ.x, TZ.y};
        sqtA = dx * dx + dy * dy + dz * dz;

        dx = px2 - (v2f){PX.z, PX.w}; dy = py2 - (v2f){PY.z, PY.w}; dz = pz2 - (v2f){PZ.z, PZ.w};
        sqpB = dx * dx + dy * dy + dz * dz;
        dx = tx2 - (v2f){TX.z, TX.w}; dy = ty2 - (v2f){TY.z, TY.w}; dz = tz2 - (v2f){TZ.z, TZ.w};
        sqtB = dx * dx + dy * dy + dz * dz;

        pair_tail(sqpA.x, sqtA.x, CT.x, sLUT, num, den);
        pair_tail(sqpA.y, sqtA.y, CT.y, sLUT, num, den);
        pair_tail(sqpB.x, sqtB.x, CT.z, sLUT, num, den);
        pair_tail(sqpB.y, sqtB.y, CT.w, sLUT, num, den);
    }

    // fold row cm_i; remove self-pair contribution on diagonal tiles
    num *= cmf;
    den *= cmf;
    if (diag && tid < TS) {   // exactly once per row i
        num -= cmf * S_DIAG;
        den -= cmf;
    }

    // ---- wave (64) then block reduction ----
    #pragma unroll
    for (int off = 32; off > 0; off >>= 1) {
        num += __shfl_down(num, off, 64);
        den += __shfl_down(den, off, 64);
    }
    const int w = tid >> 6;
    if ((tid & 63) == 0) { wnum[w] = num; wden[w] = den; }
    __syncthreads();

    if (tid == 0) {
        const float tn = wnum[0] + wnum[1] + wnum[2] + wnum[3];
        const float td = wden[0] + wden[1] + wden[2] + wden[3];
        pnum[blockIdx.x] = diag ? tn : tn * 2.0f;   // off-diagonal tiles count twice
        pden[blockIdx.x] = diag ? td : td * 2.0f;
    }
}

__global__ __launch_bounds__(256) void lddt_final_kernel(
    const float* __restrict__ pnum, const float* __restrict__ pden,
    float* __restrict__ out, int nslots)
{
    __shared__ double sn0[4], sn1[4], sd0[4], sd1[4];
    double n0 = 0, n1 = 0, d0 = 0, d1 = 0;
    for (int s = threadIdx.x; s < 2 * nslots; s += 256) {
        if (s < nslots) { n0 += (double)pnum[s]; d0 += (double)pden[s]; }
        else            { n1 += (double)pnum[s]; d1 += (double)pden[s]; }
    }
    #pragma unroll
    for (int off = 32; off > 0; off >>= 1) {
        n0 += __shfl_down(n0, off, 64); d0 += __shfl_down(d0, off, 64);
        n1 += __shfl_down(n1, off, 64); d1 += __shfl_down(d1, off, 64);
    }
    const int w = threadIdx.x >> 6;
    if ((threadIdx.x & 63) == 0) { sn0[w] = n0; sn1[w] = n1; sd0[w] = d0; sd1[w] = d1; }
    __syncthreads();
    if (threadIdx.x == 0) {
        double N0 = sn0[0] + sn0[1] + sn0[2] + sn0[3];
        double N1 = sn1[0] + sn1[1] + sn1[2] + sn1[3];
        double D0 = sd0[0] + sd0[1] + sd0[2] + sd0[3];
        double D1 = sd1[0] + sd1[1] + sd1[2] + sd1[3];
        D0 = D0 > 1.0 ? D0 : 1.0;
        D1 = D1 > 1.0 ? D1 : 1.0;
        const double l0 = 0.25 * N0 / D0;   // 0.25 = mean over 4 thresholds
        const double l1 = 0.25 * N1 / D1;
        out[0] = (float)(1.0 - 0.5 * (l0 + l1));
    }
}

extern "C" void kernel_launch(void* const* d_in, const int* in_sizes, int n_in,
                              void* d_out, int out_size, void* d_ws, size_t ws_size,
                              hipStream_t stream) {
    const float* pred = (const float*)d_in[0];
    const float* tru  = (const float*)d_in[1];
    const int*   dna  = (const int*)d_in[2];
    const int*   rna  = (const int*)d_in[3];
    const int*   cm   = (const int*)d_in[4];
    float* out = (float*)d_out;

    const int B = 2;
    const int n = in_sizes[2] / B;        // is_dna has b*n elements
    const int T = n / TS;                 // 64 tiles per row
    const int nslots = T * (T + 1) / 2;   // 2080 per batch

    float* pnum = (float*)d_ws;
    float* pden = (float*)((char*)d_ws + (size_t)B * nslots * sizeof(float));

    const int grid = B * nslots;          // triangular launch: no dead blocks

    hipLaunchKernelGGL(lddt_tile_kernel, dim3(grid), dim3(NTHREADS), 0, stream,
                       pred, tru, dna, rna, cm, pnum, pden, n, T, nslots);
    hipLaunchKernelGGL(lddt_final_kernel, dim3(1), dim3(256), 0, stream,
                       pnum, pden, out, nslots);
}